// Round 14
// baseline (43.525 us; speedup 1.0000x reference)
//
#include <hip/hip_runtime.h>
#include <cstdint>

#define IN_F 128
#define OUT_F 128
#define NPB 8        // nodes per block
#define THREADS 1024
#define TOPD 32
#define NEG_BIG -1e30f

typedef __fp16 h2v __attribute__((ext_vector_type(2)));
union H2U { unsigned u; h2v v; };
typedef _Float16 f16x8 __attribute__((ext_vector_type(8)));
typedef float f32x4 __attribute__((ext_vector_type(4)));
union F8U { unsigned u[4]; f16x8 v; };

// ---- Kernel A: exact top-32 (val,idx) per feature column, descending ----
__global__ __launch_bounds__(64, 1) void topk_kernel(
    const float* __restrict__ h, float* __restrict__ wsval,
    int* __restrict__ wsidx, int N)
{
    __shared__ float vals[1024];
    const int lane = threadIdx.x;
    const int b = blockIdx.x >> 7;
    const int f = blockIdx.x & 127;
    const float* col = h + (size_t)b * N * IN_F + f;

    float lmax = -__builtin_inff(); int lrow = 0;
    #pragma unroll
    for (int q = 0; q < 16; ++q) {
        const int r = q * 64 + lane;
        const float x = col[(size_t)r * IN_F];
        vals[r] = x;
        if (x > lmax) { lmax = x; lrow = r; }
    }
    #pragma unroll 1
    for (int d = 0; d < TOPD; ++d) {
        float rmax = lmax; int rrow = lrow;
        #pragma unroll
        for (int s = 32; s; s >>= 1) {
            const float om = __shfl_xor(rmax, s, 64);
            const int  orr = __shfl_xor(rrow, s, 64);
            if (om > rmax || (om == rmax && orr < rrow)) { rmax = om; rrow = orr; }
        }
        if (lane == 0) {
            wsval[(b * TOPD + d) * 128 + f] = rmax;   // [b][d][f] probe-coalesced
            wsidx[(b * TOPD + d) * 128 + f] = rrow;
        }
        if ((rrow & 63) == lane) {                    // winner lane: extract + recompute
            vals[rrow] = -__builtin_inff();
            lmax = -__builtin_inff(); lrow = lane;
            #pragma unroll
            for (int q = 0; q < 16; ++q) {
                const int r = q * 64 + lane;
                const float x = vals[r];
                if (x > lmax) { lmax = x; lrow = r; }
            }
        }
    }
}

// ---- Kernel B: bitmaps -> probe -> MFMA epilogue -> LN (N=1024) ----
__global__ __launch_bounds__(THREADS, 4) void sage1024_kernel(
    const float* __restrict__ h, const int* __restrict__ adj,
    const float* __restrict__ Ws, const float* __restrict__ bs,
    const float* __restrict__ Wn, const float* __restrict__ bn,
    const float* __restrict__ gamma, const float* __restrict__ beta,
    const float* __restrict__ wsval, const int* __restrict__ wsidx,
    float* __restrict__ out)
{
    const int N = 1024;
    __shared__ unsigned long long bm[NPB][16];       // 1 KB adjacency bitmaps
    __shared__ __align__(16) char Xraw[NPB * 512];   // 4 KB X[n][256] f16 swizzled
    __shared__ float outp[NPB][OUT_F];               // 4 KB
    __shared__ unsigned hasn_s[NPB];

    const int t    = threadIdx.x;
    const int w    = t >> 6;
    const int lane = t & 63;

    const int base = blockIdx.x * NPB;
    const int b    = base / N;
    const int i0   = base - b * N;
    const float* hb   = h   + (size_t)b * N * IN_F;
    const int*   adjb = adj + (size_t)b * N * N;

    // bitmap build: wave w -> node w>>1, half w&1
    {
        const int n = w >> 1, half = w & 1;
        const int i_n = i0 + n;
        const int* ar = adjb + (size_t)i_n * N;
        #pragma unroll
        for (int c = 0; c < 8; ++c) {
            const int j = half * 512 + c * 64 + lane;
            const unsigned long long word = __ballot(ar[j] != 0 && j != i_n);
            if (lane == 0) bm[n][half * 8 + c] = word;
        }
    }
    __syncthreads();
    if (t < NPB) {
        unsigned long long o = 0;
        #pragma unroll
        for (int g = 0; g < 16; ++g) o |= bm[t][g];
        hasn_s[t] = (o != 0ull) ? 1u : 0u;
    }
    __syncthreads();

    // probe: thread -> (n = t>>7, f = t&127)
    const int n = t >> 7, f = t & 127;
    const float hs = hb[(size_t)(i0 + n) * IN_F + f];
    float agg;
    if (!hasn_s[n]) {
        agg = hs;                                   // no neighbors -> self
    } else {
        agg = NEG_BIG; bool found = false;
        #pragma unroll 1
        for (int d = 0; d < TOPD && !found; ++d) {  // expected ~2, wave-max ~7
            const float v = wsval[(b * TOPD + d) * 128 + f];
            const int   j = wsidx[(b * TOPD + d) * 128 + f];
            if ((bm[n][j >> 6] >> (j & 63)) & 1ull) { agg = v; found = true; }
        }
        if (!found) {                               // exact fallback (P ~ 2^-32)
            #pragma unroll 1
            for (int g = 0; g < 16; ++g) {
                unsigned long long word = bm[n][g];
                while (word) {
                    const int r = __builtin_ctzll(word); word &= word - 1;
                    agg = fmaxf(agg, hb[(size_t)(g * 64 + r) * IN_F + f]);
                }
            }
        }
    }
    // X build: self k=f, agg k=128+f (f16, XOR-swizzled rows)
    *(__fp16*)(Xraw + (((unsigned)(n * 512 + f * 2))       ^ ((n & 7) << 4))) = (__fp16)hs;
    *(__fp16*)(Xraw + (((unsigned)(n * 512 + 256 + f * 2)) ^ ((n & 7) << 4))) = (__fp16)agg;
    __syncthreads();

    // MFMA epilogue: out(8x128) = X(8x256,f16) . [Ws;Wn](256x128,f16)
    if (w < NPB) {
        const int col = lane & 15;
        const int kg  = lane >> 4;
        f32x4 acc = {0.f, 0.f, 0.f, 0.f};
        #pragma unroll
        for (int chunk = 0; chunk < 8; ++chunk) {
            const float* Wsrc = (chunk < 4) ? Ws : Wn;
            const int kbase = (chunk & 3) * 32 + kg * 8;
            float wv[8];
            #pragma unroll
            for (int j = 0; j < 8; ++j)
                wv[j] = Wsrc[(kbase + j) * OUT_F + w * 16 + col];
            F8U af;
            #pragma unroll
            for (int j2 = 0; j2 < 4; ++j2) {
                H2U pk; pk.v = __builtin_amdgcn_cvt_pkrtz(wv[2 * j2], wv[2 * j2 + 1]);
                af.u[j2] = pk.u;
            }
            const unsigned byte = (unsigned)(col * 512 + chunk * 64 + kg * 16) ^ ((col & 7) << 4);
            const uint4 braw = *(const uint4*)(Xraw + byte);
            F8U bf; bf.u[0] = braw.x; bf.u[1] = braw.y; bf.u[2] = braw.z; bf.u[3] = braw.w;
            acc = __builtin_amdgcn_mfma_f32_16x16x32_f16(af.v, bf.v, acc, 0, 0, 0);
        }
        if (col < NPB) {
            #pragma unroll
            for (int q = 0; q < 4; ++q)
                outp[col][w * 16 + kg * 4 + q] = acc[q];
        }
    }
    __syncthreads();

    // bias + LayerNorm + ReLU (waves 0-7, node w)
    if (w < NPB) {
        float x0 = bs[lane]      + bn[lane]      + outp[w][lane];
        float x1 = bs[lane + 64] + bn[lane + 64] + outp[w][lane + 64];
        float s  = x0 + x1;
        float s2 = x0 * x0 + x1 * x1;
        #pragma unroll
        for (int d = 32; d >= 1; d >>= 1) {
            s  += __shfl_xor(s, d, 64);
            s2 += __shfl_xor(s2, d, 64);
        }
        const float mu  = s * (1.0f / OUT_F);
        const float var = s2 * (1.0f / OUT_F) - mu * mu;
        const float rs  = rsqrtf(var + 1e-5f);

        float* orow = out + (size_t)(base + w) * OUT_F;
        const float r0 = (x0 - mu) * rs * gamma[lane]      + beta[lane];
        const float r1 = (x1 - mu) * rs * gamma[lane + 64] + beta[lane + 64];
        orow[lane]      = fmaxf(r0, 0.0f);
        orow[lane + 64] = fmaxf(r1, 0.0f);
    }
}

// ---- generic fallback (N != 1024): R12-proven dense kernel ----
__global__ __launch_bounds__(THREADS, 4) void sage_generic(
    const float* __restrict__ h, const int* __restrict__ adj,
    const float* __restrict__ Ws, const float* __restrict__ bs,
    const float* __restrict__ Wn, const float* __restrict__ bn,
    const float* __restrict__ gamma, const float* __restrict__ beta,
    float* __restrict__ out, int N)
{
    const int WAVES = 16;
    const int STRIP = N / WAVES;
    __shared__ __align__(16) char spraw[16 * NPB * 64 * 4];
    auto scanp = (unsigned (*)[NPB][64])spraw;
    auto gemmp = (float (*)[NPB][OUT_F])spraw;
    __shared__ unsigned anyw_s[16];
    __shared__ float h_self[NPB][IN_F];
    __shared__ float agg_s[NPB][IN_F];

    const int t = threadIdx.x, w = t >> 6, lane = t & 63;
    const int base = blockIdx.x * NPB;
    const int b = base / N, i0 = base - b * N;
    const float* hb = h + (size_t)b * N * IN_F;
    const int* adjb = adj + (size_t)b * N * N;
    const int jbase = w * STRIP;

    unsigned long long m[NPB]; unsigned anybits = 0;
    #pragma unroll
    for (int n = 0; n < NPB; ++n) {
        const int i_n = i0 + n, j = jbase + lane;
        m[n] = __ballot(adjb[(size_t)i_n * N + j] != 0 && j != i_n);
        anybits |= (m[n] != 0ull ? 1u : 0u) << n;
    }
    const unsigned NEGINF2 = 0xFC00FC00u, POSINF2 = 0x7C007C00u;
    H2U a[NPB];
    #pragma unroll
    for (int n = 0; n < NPB; ++n) a[n].u = NEGINF2;
    const float* hrow = hb + (size_t)jbase * IN_F + 2 * lane;
    for (int k = 0; k < STRIP; ++k) {
        const float2 vf = *(const float2*)(hrow + (size_t)k * IN_F);
        H2U vp; vp.v = __builtin_amdgcn_cvt_pkrtz(vf.x, vf.y);
        #pragma unroll
        for (int n = 0; n < NPB; ++n) {
            H2U cap; cap.u = ((m[n] >> k) & 1ull) ? POSINF2 : NEGINF2;
            a[n].v = __builtin_elementwise_max(a[n].v, __builtin_elementwise_min(vp.v, cap.v));
        }
    }
    #pragma unroll
    for (int n = 0; n < NPB; ++n) scanp[w][n][lane] = a[n].u;
    if (lane == 0) anyw_s[w] = anybits;
    __syncthreads();
    if (w < NPB) {
        H2U r; r.u = scanp[0][w][lane];
        #pragma unroll
        for (int wp = 1; wp < 16; ++wp) { H2U p; p.u = scanp[wp][w][lane]; r.v = __builtin_elementwise_max(r.v, p.v); }
        unsigned anyall = 0;
        #pragma unroll
        for (int wp = 0; wp < 16; ++wp) anyall |= anyw_s[wp];
        float rx = (float)r.v.x, ry = (float)r.v.y;
        const float2 hsv = *(const float2*)&hb[(size_t)(i0 + w) * IN_F + 2 * lane];
        if (!((anyall >> w) & 1u)) { rx = hsv.x; ry = hsv.y; }
        *(float2*)&agg_s[w][2 * lane] = make_float2(rx, ry);
    } else {
        const int n2 = w - NPB;
        const float2 hsv = *(const float2*)&hb[(size_t)(i0 + n2) * IN_F + 2 * lane];
        *(float2*)&h_self[n2][2 * lane] = hsv;
    }
    __syncthreads();
    {
        const int o = t & (OUT_F - 1), fc = t >> 7;
        float acc[NPB];
        #pragma unroll
        for (int n = 0; n < NPB; ++n) acc[n] = 0.0f;
        const int f0 = fc * (IN_F / 8);
        #pragma unroll
        for (int ff = 0; ff < IN_F / 8; ++ff) {
            const int f = f0 + ff;
            const float ws = Ws[f * OUT_F + o], wn = Wn[f * OUT_F + o];
            #pragma unroll
            for (int n = 0; n < NPB; ++n) {
                acc[n] = fmaf(h_self[n][f], ws, acc[n]);
                acc[n] = fmaf(agg_s[n][f], wn, acc[n]);
            }
        }
        #pragma unroll
        for (int n = 0; n < NPB; ++n) gemmp[fc][n][o] = acc[n];
    }
    __syncthreads();
    if (w < NPB) {
        float x0 = bs[lane] + bn[lane];
        float x1 = bs[lane + 64] + bn[lane + 64];
        #pragma unroll
        for (int fcc = 0; fcc < 8; ++fcc) { x0 += gemmp[fcc][w][lane]; x1 += gemmp[fcc][w][lane + 64]; }
        float s = x0 + x1, s2 = x0 * x0 + x1 * x1;
        #pragma unroll
        for (int d = 32; d >= 1; d >>= 1) { s += __shfl_xor(s, d, 64); s2 += __shfl_xor(s2, d, 64); }
        const float mu = s * (1.0f / OUT_F);
        const float var = s2 * (1.0f / OUT_F) - mu * mu;
        const float rs = rsqrtf(var + 1e-5f);
        float* orow = out + (size_t)(base + w) * OUT_F;
        const float r0 = (x0 - mu) * rs * gamma[lane] + beta[lane];
        const float r1 = (x1 - mu) * rs * gamma[lane + 64] + beta[lane + 64];
        orow[lane] = fmaxf(r0, 0.0f);
        orow[lane + 64] = fmaxf(r1, 0.0f);
    }
}

extern "C" void kernel_launch(void* const* d_in, const int* in_sizes, int n_in,
                              void* d_out, int out_size, void* d_ws, size_t ws_size,
                              hipStream_t stream) {
    const float* h     = (const float*)d_in[0];
    const int*   adj   = (const int*)d_in[1];
    const float* Ws    = (const float*)d_in[2];
    const float* bs    = (const float*)d_in[3];
    const float* Wn    = (const float*)d_in[4];
    const float* bn    = (const float*)d_in[5];
    const float* gamma = (const float*)d_in[6];
    const float* beta  = (const float*)d_in[7];
    float* out = (float*)d_out;

    const long long bn_nodes = in_sizes[0] / IN_F;          // B*N
    const int N = (int)((long long)in_sizes[1] / bn_nodes); // adj is B*N*N
    const int B = (int)(bn_nodes / N);
    const int grid = (int)(bn_nodes / NPB);

    if (N == 1024) {
        float* wsval = (float*)d_ws;
        int*   wsidx = (int*)((char*)d_ws + (size_t)B * TOPD * 128 * 4);
        hipLaunchKernelGGL(topk_kernel, dim3(B * 128), dim3(64), 0, stream,
                           h, wsval, wsidx, N);
        hipLaunchKernelGGL(sage1024_kernel, dim3(grid), dim3(THREADS), 0, stream,
                           h, adj, Ws, bs, Wn, bn, gamma, beta, wsval, wsidx, out);
    } else {
        hipLaunchKernelGGL(sage_generic, dim3(grid), dim3(THREADS), 0, stream,
                           h, adj, Ws, bs, Wn, bn, gamma, beta, out, N);
    }
}

// Round 15
// 26.899 us; speedup vs baseline: 1.6181x; 1.6181x over previous
//
#include <hip/hip_runtime.h>
#include <cstdint>

#define IN_F 128
#define OUT_F 128
#define NPB 4        // nodes per block
#define WAVES 16
#define THREADS 1024
#define NEG_BIG -1e30f

typedef __fp16 h2v __attribute__((ext_vector_type(2)));
union H2U { unsigned u; h2v v; };
typedef _Float16 f16x8 __attribute__((ext_vector_type(8)));
typedef float f32x4 __attribute__((ext_vector_type(4)));
union F8U { unsigned u[4]; f16x8 v; };

// ---- N=1024 specialized: 32 waves/CU, split MFMA epilogue ----
__global__ __launch_bounds__(THREADS, 8) void sage1024_kernel(
    const float* __restrict__ h, const int* __restrict__ adj,
    const float* __restrict__ Ws, const float* __restrict__ bs,
    const float* __restrict__ Wn, const float* __restrict__ bn,
    const float* __restrict__ gamma, const float* __restrict__ beta,
    float* __restrict__ out)
{
    const int N = 1024;
    __shared__ unsigned scanp[WAVES][NPB][64];     // 16 KB f16x2 partials
    __shared__ __align__(16) char Xraw[2 * NPB * 512]; // 4 KB: X_self | X_agg
    __shared__ float outp[2][NPB][OUT_F];          // 4 KB self/agg GEMM halves
    __shared__ unsigned anyw_s[WAVES];

    const int t    = threadIdx.x;
    const int w    = t >> 6;
    const int lane = t & 63;

    const int base = blockIdx.x * NPB;
    const int b    = base / N;
    const int i0   = base - b * N;

    const float* hb   = h   + (size_t)b * N * IN_F;
    const int*   adjb = adj + (size_t)b * N * N;
    const int jbase   = w * 64;

    // ---- one u64 mask per node over this wave's 64-column strip ----
    unsigned long long m[NPB];
    unsigned anybits = 0;
    #pragma unroll
    for (int n = 0; n < NPB; ++n) {
        const int i_n = i0 + n;
        const int j   = jbase + lane;
        m[n] = __ballot(adjb[(size_t)i_n * N + j] != 0 && j != i_n);
        anybits |= (m[n] != 0ull ? 1u : 0u) << n;
    }

    const unsigned NEGINF2 = 0xFC00FC00u;
    const unsigned POSINF2 = 0x7C007C00u;

    H2U a[NPB];
    #pragma unroll
    for (int n = 0; n < NPB; ++n) a[n].u = NEGINF2;

    const float* hrow = hb + (size_t)jbase * IN_F + 2 * lane;

    // ---- unrolled scan: literal shifts, imm-offset groups, packed f16 ----
    #pragma unroll
    for (int g = 0; g < 8; ++g) {
        const float* p = hrow + g * 8 * IN_F;
        float2 vf[8];
        #pragma unroll
        for (int r = 0; r < 8; ++r)
            vf[r] = *(const float2*)(p + r * IN_F);
        H2U vp[8];
        #pragma unroll
        for (int r = 0; r < 8; ++r)
            vp[r].v = __builtin_amdgcn_cvt_pkrtz(vf[r].x, vf[r].y);
        #pragma unroll
        for (int r = 0; r < 8; ++r) {
            #pragma unroll
            for (int n = 0; n < NPB; ++n) {
                H2U cap;
                cap.u = ((m[n] >> (g * 8 + r)) & 1ull) ? POSINF2 : NEGINF2;
                a[n].v = __builtin_elementwise_max(a[n].v,
                             __builtin_elementwise_min(vp[r].v, cap.v));
            }
        }
    }

    #pragma unroll
    for (int n = 0; n < NPB; ++n) scanp[w][n][lane] = a[n].u;
    if (lane == 0) anyw_s[w] = anybits;
    __syncthreads();

    // ---- combine (waves 0-3) / stage X_self (waves 4-7) ----
    // X row n: byte = (n*512 + k*2) ^ (n<<4); X_agg offset +2048.
    if (w < NPB) {
        H2U r; r.u = scanp[0][w][lane];
        #pragma unroll
        for (int wp = 1; wp < WAVES; ++wp) {
            H2U p; p.u = scanp[wp][w][lane];
            r.v = __builtin_elementwise_max(r.v, p.v);
        }
        unsigned anyall = 0;
        #pragma unroll
        for (int wp = 0; wp < WAVES; ++wp) anyall |= anyw_s[wp];
        if (!((anyall >> w) & 1u)) {
            const float2 hs = *(const float2*)&hb[(size_t)(i0 + w) * IN_F + 2 * lane];
            r.v = __builtin_amdgcn_cvt_pkrtz(hs.x, hs.y);
        }
        const unsigned byte = (unsigned)(2048 + w * 512 + lane * 4) ^ ((unsigned)w << 4);
        *(unsigned*)(Xraw + byte) = r.u;
    } else if (w < 2 * NPB) {
        const int n2 = w - NPB;
        const float2 hs = *(const float2*)&hb[(size_t)(i0 + n2) * IN_F + 2 * lane];
        H2U p; p.v = __builtin_amdgcn_cvt_pkrtz(hs.x, hs.y);
        const unsigned byte = (unsigned)(n2 * 512 + lane * 4) ^ ((unsigned)n2 << 4);
        *(unsigned*)(Xraw + byte) = p.u;
    }
    __syncthreads();

    // ---- split MFMA epilogue: waves 0-7 self.Ws, waves 8-15 agg.Wn ----
    // outp[half](4x128) = X[half](4x128,f16) . W(128x128,f16)
    {
        const int half = w >> 3;                 // 0=self, 1=agg
        const int ot   = (w & 7) * 16;           // o-tile
        const float* Wsrc = half ? Wn : Ws;
        const char*  Xb   = Xraw + half * 2048;
        const int col  = lane & 15;
        const int colc = col & 3;                // clamp to 4 valid rows
        const int kg   = lane >> 4;
        f32x4 acc = {0.f, 0.f, 0.f, 0.f};
        #pragma unroll
        for (int c = 0; c < 4; ++c) {
            const int kbase = c * 32 + kg * 8;
            float wv[8];
            #pragma unroll
            for (int j = 0; j < 8; ++j)
                wv[j] = Wsrc[(kbase + j) * OUT_F + ot + col];
            F8U af;
            #pragma unroll
            for (int j2 = 0; j2 < 4; ++j2) {
                H2U pk; pk.v = __builtin_amdgcn_cvt_pkrtz(wv[2 * j2], wv[2 * j2 + 1]);
                af.u[j2] = pk.u;
            }
            const unsigned byte = (unsigned)(colc * 512 + c * 64 + kg * 16) ^ ((unsigned)colc << 4);
            const uint4 braw = *(const uint4*)(Xb + byte);
            F8U bf; bf.u[0] = braw.x; bf.u[1] = braw.y; bf.u[2] = braw.z; bf.u[3] = braw.w;
            acc = __builtin_amdgcn_mfma_f32_16x16x32_f16(af.v, bf.v, acc, 0, 0, 0);
        }
        if (col < NPB) {
            #pragma unroll
            for (int q = 0; q < 4; ++q)
                outp[half][col][ot + kg * 4 + q] = acc[q];
        }
    }
    __syncthreads();

    // ---- bias + LayerNorm + ReLU (waves 0-3, node w) ----
    if (w < NPB) {
        float x0 = bs[lane]      + bn[lane]      + outp[0][w][lane]      + outp[1][w][lane];
        float x1 = bs[lane + 64] + bn[lane + 64] + outp[0][w][lane + 64] + outp[1][w][lane + 64];
        float s  = x0 + x1;
        float s2 = x0 * x0 + x1 * x1;
        #pragma unroll
        for (int d = 32; d >= 1; d >>= 1) {
            s  += __shfl_xor(s, d, 64);
            s2 += __shfl_xor(s2, d, 64);
        }
        const float mu  = s * (1.0f / OUT_F);
        const float var = s2 * (1.0f / OUT_F) - mu * mu;
        const float rs  = rsqrtf(var + 1e-5f);

        float* orow = out + (size_t)(base + w) * OUT_F;
        const float r0 = (x0 - mu) * rs * gamma[lane]      + beta[lane];
        const float r1 = (x1 - mu) * rs * gamma[lane + 64] + beta[lane + 64];
        orow[lane]      = fmaxf(r0, 0.0f);
        orow[lane + 64] = fmaxf(r1, 0.0f);
    }
}

// ---- generic fallback (N != 1024) ----
__global__ __launch_bounds__(THREADS, 4) void sage_generic(
    const float* __restrict__ h, const int* __restrict__ adj,
    const float* __restrict__ Ws, const float* __restrict__ bs,
    const float* __restrict__ Wn, const float* __restrict__ bn,
    const float* __restrict__ gamma, const float* __restrict__ beta,
    float* __restrict__ out, int N)
{
    const int GNPB = 8;
    const int STRIP = N / 16;
    __shared__ __align__(16) char spraw[16 * 8 * 64 * 4];
    auto scanp = (unsigned (*)[8][64])spraw;
    auto gemmp = (float (*)[8][OUT_F])spraw;
    __shared__ unsigned anyw_s[16];
    __shared__ float h_self[8][IN_F];
    __shared__ float agg_s[8][IN_F];

    const int t = threadIdx.x, w = t >> 6, lane = t & 63;
    const int base = blockIdx.x * GNPB;
    const int b = base / N, i0 = base - b * N;
    const float* hb = h + (size_t)b * N * IN_F;
    const int* adjb = adj + (size_t)b * N * N;
    const int jbase = w * STRIP;

    unsigned long long m[8]; unsigned anybits = 0;
    #pragma unroll
    for (int n = 0; n < GNPB; ++n) {
        const int i_n = i0 + n, j = jbase + lane;
        m[n] = __ballot(adjb[(size_t)i_n * N + j] != 0 && j != i_n);
        anybits |= (m[n] != 0ull ? 1u : 0u) << n;
    }
    const unsigned NEGINF2 = 0xFC00FC00u, POSINF2 = 0x7C007C00u;
    H2U a[8];
    #pragma unroll
    for (int n = 0; n < GNPB; ++n) a[n].u = NEGINF2;
    const float* hrow = hb + (size_t)jbase * IN_F + 2 * lane;
    for (int k = 0; k < STRIP; ++k) {
        const float2 vf = *(const float2*)(hrow + (size_t)k * IN_F);
        H2U vp; vp.v = __builtin_amdgcn_cvt_pkrtz(vf.x, vf.y);
        #pragma unroll
        for (int n = 0; n < GNPB; ++n) {
            H2U cap; cap.u = ((m[n] >> k) & 1ull) ? POSINF2 : NEGINF2;
            a[n].v = __builtin_elementwise_max(a[n].v, __builtin_elementwise_min(vp.v, cap.v));
        }
    }
    #pragma unroll
    for (int n = 0; n < GNPB; ++n) scanp[w][n][lane] = a[n].u;
    if (lane == 0) anyw_s[w] = anybits;
    __syncthreads();
    if (w < GNPB) {
        H2U r; r.u = scanp[0][w][lane];
        #pragma unroll
        for (int wp = 1; wp < 16; ++wp) { H2U p; p.u = scanp[wp][w][lane]; r.v = __builtin_elementwise_max(r.v, p.v); }
        unsigned anyall = 0;
        #pragma unroll
        for (int wp = 0; wp < 16; ++wp) anyall |= anyw_s[wp];
        float rx = (float)r.v.x, ry = (float)r.v.y;
        const float2 hsv = *(const float2*)&hb[(size_t)(i0 + w) * IN_F + 2 * lane];
        if (!((anyall >> w) & 1u)) { rx = hsv.x; ry = hsv.y; }
        *(float2*)&agg_s[w][2 * lane] = make_float2(rx, ry);
    } else {
        const int n2 = w - GNPB;
        const float2 hsv = *(const float2*)&hb[(size_t)(i0 + n2) * IN_F + 2 * lane];
        *(float2*)&h_self[n2][2 * lane] = hsv;
    }
    __syncthreads();
    {
        const int o = t & (OUT_F - 1), fc = t >> 7;
        float acc[8];
        #pragma unroll
        for (int n = 0; n < GNPB; ++n) acc[n] = 0.0f;
        const int f0 = fc * (IN_F / 8);
        #pragma unroll
        for (int ff = 0; ff < IN_F / 8; ++ff) {
            const int f = f0 + ff;
            const float ws = Ws[f * OUT_F + o], wn = Wn[f * OUT_F + o];
            #pragma unroll
            for (int n = 0; n < GNPB; ++n) {
                acc[n] = fmaf(h_self[n][f], ws, acc[n]);
                acc[n] = fmaf(agg_s[n][f], wn, acc[n]);
            }
        }
        #pragma unroll
        for (int n = 0; n < GNPB; ++n) gemmp[fc][n][o] = acc[n];
    }
    __syncthreads();
    if (w < GNPB) {
        float x0 = bs[lane] + bn[lane];
        float x1 = bs[lane + 64] + bn[lane + 64];
        #pragma unroll
        for (int fcc = 0; fcc < 8; ++fcc) { x0 += gemmp[fcc][w][lane]; x1 += gemmp[fcc][w][lane + 64]; }
        float s = x0 + x1, s2 = x0 * x0 + x1 * x1;
        #pragma unroll
        for (int d = 32; d >= 1; d >>= 1) { s += __shfl_xor(s, d, 64); s2 += __shfl_xor(s2, d, 64); }
        const float mu = s * (1.0f / OUT_F);
        const float var = s2 * (1.0f / OUT_F) - mu * mu;
        const float rs = rsqrtf(var + 1e-5f);
        float* orow = out + (size_t)(base + w) * OUT_F;
        const float r0 = (x0 - mu) * rs * gamma[lane] + beta[lane];
        const float r1 = (x1 - mu) * rs * gamma[lane + 64] + beta[lane + 64];
        orow[lane] = fmaxf(r0, 0.0f);
        orow[lane + 64] = fmaxf(r1, 0.0f);
    }
}

extern "C" void kernel_launch(void* const* d_in, const int* in_sizes, int n_in,
                              void* d_out, int out_size, void* d_ws, size_t ws_size,
                              hipStream_t stream) {
    const float* h     = (const float*)d_in[0];
    const int*   adj   = (const int*)d_in[1];
    const float* Ws    = (const float*)d_in[2];
    const float* bs    = (const float*)d_in[3];
    const float* Wn    = (const float*)d_in[4];
    const float* bn    = (const float*)d_in[5];
    const float* gamma = (const float*)d_in[6];
    const float* beta  = (const float*)d_in[7];
    float* out = (float*)d_out;

    const long long bn_nodes = in_sizes[0] / IN_F;          // B*N
    const int N = (int)((long long)in_sizes[1] / bn_nodes); // adj is B*N*N

    if (N == 1024) {
        const int grid = (int)(bn_nodes / NPB);             // 512
        hipLaunchKernelGGL(sage1024_kernel, dim3(grid), dim3(THREADS), 0, stream,
                           h, adj, Ws, bs, Wn, bn, gamma, beta, out);
    } else {
        const int grid = (int)(bn_nodes / 8);
        hipLaunchKernelGGL(sage_generic, dim3(grid), dim3(THREADS), 0, stream,
                           h, adj, Ws, bs, Wn, bn, gamma, beta, out, N);
    }
}

// Round 16
// 24.999 us; speedup vs baseline: 1.7411x; 1.0760x over previous
//
#include <hip/hip_runtime.h>
#include <cstdint>

#define IN_F 128
#define OUT_F 128
#define NPB 8
#define THREADS 1024
#define TOPD 32
#define NEG_BIG -1e30f

typedef __fp16 h2v __attribute__((ext_vector_type(2)));
union H2U { unsigned u; h2v v; };
typedef _Float16 f16x8 __attribute__((ext_vector_type(8)));
typedef float f32x4 __attribute__((ext_vector_type(4)));
union F8U { unsigned u[4]; f16x8 v; };

__device__ __forceinline__ unsigned mono(float x) {   // order-preserving f32->u32
    unsigned u = __float_as_uint(x);
    return u ^ ((unsigned)((int)u >> 31) | 0x80000000u);
}

// ---- Kernel A: top-32 (val,row) per feature column, emitted ~descending ----
__global__ __launch_bounds__(64) void topk_kernel(
    const float* __restrict__ h, float* __restrict__ wsval,
    int* __restrict__ wsidx, int N)
{
    __shared__ float sv[64][16];
    __shared__ unsigned short si[64][16];
    const int lane = threadIdx.x;
    const int b = blockIdx.x >> 7;
    const int f = blockIdx.x & 127;
    const float* col = h + (size_t)b * N * IN_F + f;

    float v[16]; int ix[16];
    #pragma unroll
    for (int q = 0; q < 16; ++q) {
        v[q] = col[(size_t)(q * 64 + lane) * IN_F];
        ix[q] = q * 64 + lane;
    }
    // odd-even transposition sort (descending), all-static indices
    #pragma unroll
    for (int ph = 0; ph < 16; ++ph) {
        #pragma unroll
        for (int i = (ph & 1); i + 1 < 16; i += 2) {
            if (v[i] < v[i + 1]) {
                float tv = v[i]; v[i] = v[i + 1]; v[i + 1] = tv;
                int ti = ix[i]; ix[i] = ix[i + 1]; ix[i + 1] = ti;
            }
        }
    }
    #pragma unroll
    for (int q = 0; q < 16; ++q) { sv[lane][q] = v[q]; si[lane][q] = (unsigned short)ix[q]; }

    int head = 0;
    float curval = v[0];
    unsigned cur = (mono(curval) & 0xFFFFFFC0u) | (unsigned)lane;  // key|lane

    #pragma unroll 1
    for (int d = 0; d < TOPD; ++d) {
        unsigned k = cur;
        #pragma unroll
        for (int s = 32; s; s >>= 1) {
            const unsigned o = __shfl_xor(k, s, 64);
            k = (o > k) ? o : k;
        }
        if ((k & 63u) == (unsigned)lane) {   // this lane's head won
            wsval[((size_t)b * TOPD + d) * 128 + f] = curval;
            wsidx[((size_t)b * TOPD + d) * 128 + f] = (int)si[lane][head];
            ++head;
            if (head < 16) {
                curval = sv[lane][head];
                cur = (mono(curval) & 0xFFFFFFC0u) | (unsigned)lane;
            } else {
                curval = NEG_BIG;
                cur = 0u;
            }
        }
    }
}

// ---- Kernel B: bitmaps -> sorted-probe agg -> MFMA epilogue -> LN ----
__global__ __launch_bounds__(THREADS, 4) void sage1024_kernel(
    const float* __restrict__ h, const int* __restrict__ adj,
    const float* __restrict__ Ws, const float* __restrict__ bs,
    const float* __restrict__ Wn, const float* __restrict__ bn,
    const float* __restrict__ gamma, const float* __restrict__ beta,
    const float* __restrict__ wsval, const int* __restrict__ wsidx,
    float* __restrict__ out)
{
    const int N = 1024;
    __shared__ unsigned long long bm[NPB][16];       // 1 KB adjacency bitmaps
    __shared__ __align__(16) char Xraw[NPB * 512];   // 4 KB X[n][256] f16 swizzled
    __shared__ float outp[NPB][OUT_F];               // 4 KB
    __shared__ unsigned hasn_s[NPB];

    const int t    = threadIdx.x;
    const int w    = t >> 6;
    const int lane = t & 63;

    const int base = blockIdx.x * NPB;
    const int b    = base / N;
    const int i0   = base - b * N;
    const float* hb   = h   + (size_t)b * N * IN_F;
    const int*   adjb = adj + (size_t)b * N * N;

    // bitmap build: wave w -> node w>>1, half w&1
    {
        const int n = w >> 1, half = w & 1;
        const int i_n = i0 + n;
        const int* ar = adjb + (size_t)i_n * N;
        #pragma unroll
        for (int c = 0; c < 8; ++c) {
            const int j = half * 512 + c * 64 + lane;
            const unsigned long long word = __ballot(ar[j] != 0 && j != i_n);
            if (lane == 0) bm[n][half * 8 + c] = word;
        }
    }
    __syncthreads();
    if (t < NPB) {
        unsigned long long o = 0;
        #pragma unroll
        for (int g = 0; g < 16; ++g) o |= bm[t][g];
        hasn_s[t] = (o != 0ull) ? 1u : 0u;
    }
    __syncthreads();

    // probe: thread -> (n = t>>7, f = t&127); wave shares n
    const int n = t >> 7, f = t & 127;
    const float hs = hb[(size_t)(i0 + n) * IN_F + f];
    float agg = hs;                                   // no-neighbor default
    if (hasn_s[n]) {
        bool found = false;
        float av = NEG_BIG;
        #pragma unroll 1
        for (int dg = 0; dg < TOPD / 4; ++dg) {       // groups of 4 probes
            float pv[4]; int pi[4];
            #pragma unroll
            for (int j = 0; j < 4; ++j) {             // coalesced prefetch
                const int d = dg * 4 + j;
                pv[j] = wsval[((size_t)b * TOPD + d) * 128 + f];
                pi[j] = wsidx[((size_t)b * TOPD + d) * 128 + f];
            }
            #pragma unroll
            for (int j = 0; j < 4; ++j) {
                const unsigned long long wbits = bm[n][pi[j] >> 6];
                const bool hit = (wbits >> (pi[j] & 63)) & 1ull;
                if (!found && hit) { av = pv[j]; found = true; }
            }
            if (__all(found)) break;
        }
        const unsigned long long miss = __ballot(!found);
        if (miss) {                                   // exact cooperative fallback (~never)
            float acc = NEG_BIG;
            #pragma unroll 1
            for (int g = 0; g < 16; ++g) {
                unsigned long long word = bm[n][g];
                const int gbase = g * 64;
                while (word) {
                    const int r = __builtin_ctzll(word); word &= word - 1;
                    acc = fmaxf(acc, hb[(size_t)(gbase + r) * IN_F + f]);  // coalesced
                }
            }
            if (!found) av = acc;
        }
        agg = av;
    }

    // X build: self k=f, agg k=128+f (f16, XOR-swizzled rows)
    *(__fp16*)(Xraw + (((unsigned)(n * 512 + f * 2))       ^ ((n & 7) << 4))) = (__fp16)hs;
    *(__fp16*)(Xraw + (((unsigned)(n * 512 + 256 + f * 2)) ^ ((n & 7) << 4))) = (__fp16)agg;
    __syncthreads();

    // MFMA epilogue: out(8x128) = X(8x256,f16) . [Ws;Wn](256x128,f16)
    if (w < NPB) {
        const int col = lane & 15;
        const int kg  = lane >> 4;
        f32x4 acc = {0.f, 0.f, 0.f, 0.f};
        #pragma unroll
        for (int chunk = 0; chunk < 8; ++chunk) {
            const float* Wsrc = (chunk < 4) ? Ws : Wn;
            const int kbase = (chunk & 3) * 32 + kg * 8;
            float wv[8];
            #pragma unroll
            for (int j = 0; j < 8; ++j)
                wv[j] = Wsrc[(kbase + j) * OUT_F + w * 16 + col];
            F8U af;
            #pragma unroll
            for (int j2 = 0; j2 < 4; ++j2) {
                H2U pk; pk.v = __builtin_amdgcn_cvt_pkrtz(wv[2 * j2], wv[2 * j2 + 1]);
                af.u[j2] = pk.u;
            }
            const unsigned byte = (unsigned)(col * 512 + chunk * 64 + kg * 16) ^ ((col & 7) << 4);
            const uint4 braw = *(const uint4*)(Xraw + byte);
            F8U bf; bf.u[0] = braw.x; bf.u[1] = braw.y; bf.u[2] = braw.z; bf.u[3] = braw.w;
            acc = __builtin_amdgcn_mfma_f32_16x16x32_f16(af.v, bf.v, acc, 0, 0, 0);
        }
        if (col < NPB) {
            #pragma unroll
            for (int q = 0; q < 4; ++q)
                outp[col][w * 16 + kg * 4 + q] = acc[q];
        }
    }
    __syncthreads();

    // bias + LayerNorm + ReLU (waves 0-7, node w)
    if (w < NPB) {
        float x0 = bs[lane]      + bn[lane]      + outp[w][lane];
        float x1 = bs[lane + 64] + bn[lane + 64] + outp[w][lane + 64];
        float s  = x0 + x1;
        float s2 = x0 * x0 + x1 * x1;
        #pragma unroll
        for (int d = 32; d >= 1; d >>= 1) {
            s  += __shfl_xor(s, d, 64);
            s2 += __shfl_xor(s2, d, 64);
        }
        const float mu  = s * (1.0f / OUT_F);
        const float var = s2 * (1.0f / OUT_F) - mu * mu;
        const float rs  = rsqrtf(var + 1e-5f);

        float* orow = out + (size_t)(base + w) * OUT_F;
        const float r0 = (x0 - mu) * rs * gamma[lane]      + beta[lane];
        const float r1 = (x1 - mu) * rs * gamma[lane + 64] + beta[lane + 64];
        orow[lane]      = fmaxf(r0, 0.0f);
        orow[lane + 64] = fmaxf(r1, 0.0f);
    }
}

// ---- generic fallback (N != 1024): R12-proven dense kernel ----
__global__ __launch_bounds__(THREADS, 4) void sage_generic(
    const float* __restrict__ h, const int* __restrict__ adj,
    const float* __restrict__ Ws, const float* __restrict__ bs,
    const float* __restrict__ Wn, const float* __restrict__ bn,
    const float* __restrict__ gamma, const float* __restrict__ beta,
    float* __restrict__ out, int N)
{
    const int STRIP = N / 16;
    __shared__ __align__(16) char spraw[16 * 8 * 64 * 4];
    auto scanp = (unsigned (*)[8][64])spraw;
    auto gemmp = (float (*)[8][OUT_F])spraw;
    __shared__ unsigned anyw_s[16];
    __shared__ float h_self[8][IN_F];
    __shared__ float agg_s[8][IN_F];

    const int t = threadIdx.x, w = t >> 6, lane = t & 63;
    const int base = blockIdx.x * 8;
    const int b = base / N, i0 = base - b * N;
    const float* hb = h + (size_t)b * N * IN_F;
    const int* adjb = adj + (size_t)b * N * N;
    const int jbase = w * STRIP;

    unsigned long long m[8]; unsigned anybits = 0;
    #pragma unroll
    for (int n = 0; n < 8; ++n) {
        const int i_n = i0 + n, j = jbase + lane;
        m[n] = __ballot(adjb[(size_t)i_n * N + j] != 0 && j != i_n);
        anybits |= (m[n] != 0ull ? 1u : 0u) << n;
    }
    const unsigned NEGINF2 = 0xFC00FC00u, POSINF2 = 0x7C007C00u;
    H2U a[8];
    #pragma unroll
    for (int n = 0; n < 8; ++n) a[n].u = NEGINF2;
    const float* hrow = hb + (size_t)jbase * IN_F + 2 * lane;
    for (int k = 0; k < STRIP; ++k) {
        const float2 vf = *(const float2*)(hrow + (size_t)k * IN_F);
        H2U vp; vp.v = __builtin_amdgcn_cvt_pkrtz(vf.x, vf.y);
        #pragma unroll
        for (int n = 0; n < 8; ++n) {
            H2U cap; cap.u = ((m[n] >> k) & 1ull) ? POSINF2 : NEGINF2;
            a[n].v = __builtin_elementwise_max(a[n].v, __builtin_elementwise_min(vp.v, cap.v));
        }
    }
    #pragma unroll
    for (int n = 0; n < 8; ++n) scanp[w][n][lane] = a[n].u;
    if (lane == 0) anyw_s[w] = anybits;
    __syncthreads();
    if (w < 8) {
        H2U r; r.u = scanp[0][w][lane];
        #pragma unroll
        for (int wp = 1; wp < 16; ++wp) { H2U p; p.u = scanp[wp][w][lane]; r.v = __builtin_elementwise_max(r.v, p.v); }
        unsigned anyall = 0;
        #pragma unroll
        for (int wp = 0; wp < 16; ++wp) anyall |= anyw_s[wp];
        float rx = (float)r.v.x, ry = (float)r.v.y;
        const float2 hsv = *(const float2*)&hb[(size_t)(i0 + w) * IN_F + 2 * lane];
        if (!((anyall >> w) & 1u)) { rx = hsv.x; ry = hsv.y; }
        *(float2*)&agg_s[w][2 * lane] = make_float2(rx, ry);
    } else {
        const int n2 = w - 8;
        const float2 hsv = *(const float2*)&hb[(size_t)(i0 + n2) * IN_F + 2 * lane];
        *(float2*)&h_self[n2][2 * lane] = hsv;
    }
    __syncthreads();
    {
        const int o = t & (OUT_F - 1), fc = t >> 7;
        float acc[8];
        #pragma unroll
        for (int n = 0; n < 8; ++n) acc[n] = 0.0f;
        const int f0 = fc * (IN_F / 8);
        #pragma unroll
        for (int ff = 0; ff < IN_F / 8; ++ff) {
            const int f = f0 + ff;
            const float ws = Ws[f * OUT_F + o], wn = Wn[f * OUT_F + o];
            #pragma unroll
            for (int n = 0; n < 8; ++n) {
                acc[n] = fmaf(h_self[n][f], ws, acc[n]);
                acc[n] = fmaf(agg_s[n][f], wn, acc[n]);
            }
        }
        #pragma unroll
        for (int n = 0; n < 8; ++n) gemmp[fc][n][o] = acc[n];
    }
    __syncthreads();
    if (w < 8) {
        float x0 = bs[lane] + bn[lane];
        float x1 = bs[lane + 64] + bn[lane + 64];
        #pragma unroll
        for (int fcc = 0; fcc < 8; ++fcc) { x0 += gemmp[fcc][w][lane]; x1 += gemmp[fcc][w][lane + 64]; }
        float s = x0 + x1, s2 = x0 * x0 + x1 * x1;
        #pragma unroll
        for (int d = 32; d >= 1; d >>= 1) { s += __shfl_xor(s, d, 64); s2 += __shfl_xor(s2, d, 64); }
        const float mu = s * (1.0f / OUT_F);
        const float var = s2 * (1.0f / OUT_F) - mu * mu;
        const float rs = rsqrtf(var + 1e-5f);
        float* orow = out + (size_t)(base + w) * OUT_F;
        const float r0 = (x0 - mu) * rs * gamma[lane] + beta[lane];
        const float r1 = (x1 - mu) * rs * gamma[lane + 64] + beta[lane + 64];
        orow[lane] = fmaxf(r0, 0.0f);
        orow[lane + 64] = fmaxf(r1, 0.0f);
    }
}

extern "C" void kernel_launch(void* const* d_in, const int* in_sizes, int n_in,
                              void* d_out, int out_size, void* d_ws, size_t ws_size,
                              hipStream_t stream) {
    const float* h     = (const float*)d_in[0];
    const int*   adj   = (const int*)d_in[1];
    const float* Ws    = (const float*)d_in[2];
    const float* bs    = (const float*)d_in[3];
    const float* Wn    = (const float*)d_in[4];
    const float* bn    = (const float*)d_in[5];
    const float* gamma = (const float*)d_in[6];
    const float* beta  = (const float*)d_in[7];
    float* out = (float*)d_out;

    const long long bn_nodes = in_sizes[0] / IN_F;          // B*N
    const int N = (int)((long long)in_sizes[1] / bn_nodes); // adj is B*N*N
    const int B = (int)(bn_nodes / N);
    const int grid = (int)(bn_nodes / NPB);

    if (N == 1024) {
        float* wsval = (float*)d_ws;
        int*   wsidx = (int*)((char*)d_ws + (size_t)B * TOPD * 128 * 4);
        hipLaunchKernelGGL(topk_kernel, dim3(B * 128), dim3(64), 0, stream,
                           h, wsval, wsidx, N);
        hipLaunchKernelGGL(sage1024_kernel, dim3(grid), dim3(THREADS), 0, stream,
                           h, adj, Ws, bs, Wn, bn, gamma, beta, wsval, wsidx, out);
    } else {
        hipLaunchKernelGGL(sage_generic, dim3(grid), dim3(THREADS), 0, stream,
                           h, adj, Ws, bs, Wn, bn, gamma, beta, out, N);
    }
}

// Round 17
// 24.953 us; speedup vs baseline: 1.7443x; 1.0018x over previous
//
#include <hip/hip_runtime.h>
#include <cstdint>

#define IN_F 128
#define OUT_F 128
#define NPB 8
#define THREADS 1024
#define TOPD 32
#define NEG_BIG -1e30f

typedef __fp16 h2v __attribute__((ext_vector_type(2)));
union H2U { unsigned u; h2v v; };
typedef _Float16 f16x8 __attribute__((ext_vector_type(8)));
typedef float f32x4 __attribute__((ext_vector_type(4)));
union F8U { unsigned u[4]; f16x8 v; };

__device__ __forceinline__ unsigned mono(float x) {   // order-preserving f32->u32
    unsigned u = __float_as_uint(x);
    return u ^ ((unsigned)((int)u >> 31) | 0x80000000u);
}

// ---- Kernel A: top-32 (val,row) per feature column, all-register hot loop ----
__global__ __launch_bounds__(64) void topk_kernel(
    const float* __restrict__ h, float* __restrict__ wsval,
    int* __restrict__ wsidx, int N)
{
    const int lane = threadIdx.x;
    const int b = blockIdx.x >> 7;
    const int f = blockIdx.x & 127;
    const float* col = h + (size_t)b * N * IN_F + f;

    float v[16]; unsigned k[16];
    #pragma unroll
    for (int q = 0; q < 16; ++q) {
        const int r = q * 64 + lane;
        v[q] = col[(size_t)r * IN_F];
        k[q] = (mono(v[q]) & 0xFFFFFC00u) | (unsigned)r;   // key | row (rows unique)
    }
    // odd-even transposition sort, descending by key, all-static indices
    #pragma unroll
    for (int ph = 0; ph < 16; ++ph) {
        #pragma unroll
        for (int i = (ph & 1); i + 1 < 16; i += 2) {
            const bool sw = k[i] < k[i + 1];
            const unsigned tk = k[i]; const float tv = v[i];
            k[i]     = sw ? k[i + 1] : k[i];     v[i]     = sw ? v[i + 1] : v[i];
            k[i + 1] = sw ? tk       : k[i + 1]; v[i + 1] = sw ? tv       : v[i + 1];
        }
    }
    // 32 extraction rounds: wave-max over heads, winner emits + register-shift pop
    #pragma unroll 1
    for (int d = 0; d < TOPD; ++d) {
        unsigned kk = k[0];
        #pragma unroll
        for (int s = 32; s; s >>= 1) {
            const unsigned o = __shfl_xor(kk, s, 64);
            kk = (o > kk) ? o : kk;
        }
        if (k[0] == kk) {                    // unique winner (row embedded in key)
            wsval[((size_t)b * TOPD + d) * 128 + f] = v[0];          // exact f32
            wsidx[((size_t)b * TOPD + d) * 128 + f] = (int)(kk & 1023u);
            #pragma unroll
            for (int i = 0; i + 1 < 16; ++i) { k[i] = k[i + 1]; v[i] = v[i + 1]; }
            k[15] = 0u; v[15] = NEG_BIG;
        }
    }
}

// ---- Kernel B: bitmaps -> sorted-probe agg -> MFMA epilogue -> LN ----
__global__ __launch_bounds__(THREADS, 4) void sage1024_kernel(
    const float* __restrict__ h, const int* __restrict__ adj,
    const float* __restrict__ Ws, const float* __restrict__ bs,
    const float* __restrict__ Wn, const float* __restrict__ bn,
    const float* __restrict__ gamma, const float* __restrict__ beta,
    const float* __restrict__ wsval, const int* __restrict__ wsidx,
    float* __restrict__ out)
{
    const int N = 1024;
    __shared__ unsigned long long bm[NPB][16];       // 1 KB adjacency bitmaps
    __shared__ __align__(16) char Xraw[NPB * 512];   // 4 KB X[n][256] f16 swizzled
    __shared__ float outp[NPB][OUT_F];               // 4 KB
    __shared__ unsigned hasn_s[NPB];

    const int t    = threadIdx.x;
    const int w    = t >> 6;
    const int lane = t & 63;

    const int base = blockIdx.x * NPB;
    const int b    = base / N;
    const int i0   = base - b * N;
    const float* hb   = h   + (size_t)b * N * IN_F;
    const int*   adjb = adj + (size_t)b * N * N;

    // bitmap build: wave w -> node w>>1, half w&1
    {
        const int n = w >> 1, half = w & 1;
        const int i_n = i0 + n;
        const int* ar = adjb + (size_t)i_n * N;
        #pragma unroll
        for (int c = 0; c < 8; ++c) {
            const int j = half * 512 + c * 64 + lane;
            const unsigned long long word = __ballot(ar[j] != 0 && j != i_n);
            if (lane == 0) bm[n][half * 8 + c] = word;
        }
    }
    __syncthreads();
    if (t < NPB) {
        unsigned long long o = 0;
        #pragma unroll
        for (int g = 0; g < 16; ++g) o |= bm[t][g];
        hasn_s[t] = (o != 0ull) ? 1u : 0u;
    }
    __syncthreads();

    // probe: thread -> (n = t>>7, f = t&127); wave shares n
    const int n = t >> 7, f = t & 127;
    const float hs = hb[(size_t)(i0 + n) * IN_F + f];
    float agg = hs;                                   // no-neighbor default
    if (hasn_s[n]) {
        bool found = false;
        float av = NEG_BIG;
        #pragma unroll 1
        for (int dg = 0; dg < TOPD / 4; ++dg) {       // groups of 4 probes
            float pv[4]; int pi[4];
            #pragma unroll
            for (int j = 0; j < 4; ++j) {             // coalesced prefetch
                const int d = dg * 4 + j;
                pv[j] = wsval[((size_t)b * TOPD + d) * 128 + f];
                pi[j] = wsidx[((size_t)b * TOPD + d) * 128 + f];
            }
            #pragma unroll
            for (int j = 0; j < 4; ++j) {
                const unsigned long long wbits = bm[n][pi[j] >> 6];
                const bool hit = (wbits >> (pi[j] & 63)) & 1ull;
                if (!found && hit) { av = pv[j]; found = true; }
            }
            if (__all(found)) break;
        }
        const unsigned long long miss = __ballot(!found);
        if (miss) {                                   // exact fallback (~never taken)
            float acc = NEG_BIG;
            #pragma unroll 1
            for (int g = 0; g < 16; ++g) {
                unsigned long long word = bm[n][g];
                const int gbase = g * 64;
                while (word) {
                    const int r = __builtin_ctzll(word); word &= word - 1;
                    acc = fmaxf(acc, hb[(size_t)(gbase + r) * IN_F + f]);
                }
            }
            if (!found) av = acc;
        }
        agg = av;
    }

    // X build: self k=f, agg k=128+f (f16, XOR-swizzled rows)
    *(__fp16*)(Xraw + (((unsigned)(n * 512 + f * 2))       ^ ((n & 7) << 4))) = (__fp16)hs;
    *(__fp16*)(Xraw + (((unsigned)(n * 512 + 256 + f * 2)) ^ ((n & 7) << 4))) = (__fp16)agg;
    __syncthreads();

    // MFMA epilogue: out(8x128) = X(8x256,f16) . [Ws;Wn](256x128,f16)
    if (w < NPB) {
        const int col = lane & 15;
        const int kg  = lane >> 4;
        f32x4 acc = {0.f, 0.f, 0.f, 0.f};
        #pragma unroll
        for (int chunk = 0; chunk < 8; ++chunk) {
            const float* Wsrc = (chunk < 4) ? Ws : Wn;
            const int kbase = (chunk & 3) * 32 + kg * 8;
            float wv[8];
            #pragma unroll
            for (int j = 0; j < 8; ++j)
                wv[j] = Wsrc[(kbase + j) * OUT_F + w * 16 + col];
            F8U af;
            #pragma unroll
            for (int j2 = 0; j2 < 4; ++j2) {
                H2U pk; pk.v = __builtin_amdgcn_cvt_pkrtz(wv[2 * j2], wv[2 * j2 + 1]);
                af.u[j2] = pk.u;
            }
            const unsigned byte = (unsigned)(col * 512 + chunk * 64 + kg * 16) ^ ((col & 7) << 4);
            const uint4 braw = *(const uint4*)(Xraw + byte);
            F8U bf; bf.u[0] = braw.x; bf.u[1] = braw.y; bf.u[2] = braw.z; bf.u[3] = braw.w;
            acc = __builtin_amdgcn_mfma_f32_16x16x32_f16(af.v, bf.v, acc, 0, 0, 0);
        }
        if (col < NPB) {
            #pragma unroll
            for (int q = 0; q < 4; ++q)
                outp[col][w * 16 + kg * 4 + q] = acc[q];
        }
    }
    __syncthreads();

    // bias + LayerNorm + ReLU (waves 0-7, node w)
    if (w < NPB) {
        float x0 = bs[lane]      + bn[lane]      + outp[w][lane];
        float x1 = bs[lane + 64] + bn[lane + 64] + outp[w][lane + 64];
        float s  = x0 + x1;
        float s2 = x0 * x0 + x1 * x1;
        #pragma unroll
        for (int d = 32; d >= 1; d >>= 1) {
            s  += __shfl_xor(s, d, 64);
            s2 += __shfl_xor(s2, d, 64);
        }
        const float mu  = s * (1.0f / OUT_F);
        const float var = s2 * (1.0f / OUT_F) - mu * mu;
        const float rs  = rsqrtf(var + 1e-5f);

        float* orow = out + (size_t)(base + w) * OUT_F;
        const float r0 = (x0 - mu) * rs * gamma[lane]      + beta[lane];
        const float r1 = (x1 - mu) * rs * gamma[lane + 64] + beta[lane + 64];
        orow[lane]      = fmaxf(r0, 0.0f);
        orow[lane + 64] = fmaxf(r1, 0.0f);
    }
}

// ---- generic fallback (N != 1024): R12-proven dense kernel ----
__global__ __launch_bounds__(THREADS, 4) void sage_generic(
    const float* __restrict__ h, const int* __restrict__ adj,
    const float* __restrict__ Ws, const float* __restrict__ bs,
    const float* __restrict__ Wn, const float* __restrict__ bn,
    const float* __restrict__ gamma, const float* __restrict__ beta,
    float* __restrict__ out, int N)
{
    const int STRIP = N / 16;
    __shared__ __align__(16) char spraw[16 * 8 * 64 * 4];
    auto scanp = (unsigned (*)[8][64])spraw;
    auto gemmp = (float (*)[8][OUT_F])spraw;
    __shared__ unsigned anyw_s[16];
    __shared__ float h_self[8][IN_F];
    __shared__ float agg_s[8][IN_F];

    const int t = threadIdx.x, w = t >> 6, lane = t & 63;
    const int base = blockIdx.x * 8;
    const int b = base / N, i0 = base - b * N;
    const float* hb = h + (size_t)b * N * IN_F;
    const int* adjb = adj + (size_t)b * N * N;
    const int jbase = w * STRIP;

    unsigned long long m[8]; unsigned anybits = 0;
    #pragma unroll
    for (int n = 0; n < 8; ++n) {
        const int i_n = i0 + n, j = jbase + lane;
        m[n] = __ballot(adjb[(size_t)i_n * N + j] != 0 && j != i_n);
        anybits |= (m[n] != 0ull ? 1u : 0u) << n;
    }
    const unsigned NEGINF2 = 0xFC00FC00u, POSINF2 = 0x7C007C00u;
    H2U a[8];
    #pragma unroll
    for (int n = 0; n < 8; ++n) a[n].u = NEGINF2;
    const float* hrow = hb + (size_t)jbase * IN_F + 2 * lane;
    for (int k = 0; k < STRIP; ++k) {
        const float2 vf = *(const float2*)(hrow + (size_t)k * IN_F);
        H2U vp; vp.v = __builtin_amdgcn_cvt_pkrtz(vf.x, vf.y);
        #pragma unroll
        for (int n = 0; n < 8; ++n) {
            H2U cap; cap.u = ((m[n] >> k) & 1ull) ? POSINF2 : NEGINF2;
            a[n].v = __builtin_elementwise_max(a[n].v, __builtin_elementwise_min(vp.v, cap.v));
        }
    }
    #pragma unroll
    for (int n = 0; n < 8; ++n) scanp[w][n][lane] = a[n].u;
    if (lane == 0) anyw_s[w] = anybits;
    __syncthreads();
    if (w < 8) {
        H2U r; r.u = scanp[0][w][lane];
        #pragma unroll
        for (int wp = 1; wp < 16; ++wp) { H2U p; p.u = scanp[wp][w][lane]; r.v = __builtin_elementwise_max(r.v, p.v); }
        unsigned anyall = 0;
        #pragma unroll
        for (int wp = 0; wp < 16; ++wp) anyall |= anyw_s[wp];
        float rx = (float)r.v.x, ry = (float)r.v.y;
        const float2 hsv = *(const float2*)&hb[(size_t)(i0 + w) * IN_F + 2 * lane];
        if (!((anyall >> w) & 1u)) { rx = hsv.x; ry = hsv.y; }
        *(float2*)&agg_s[w][2 * lane] = make_float2(rx, ry);
    } else {
        const int n2 = w - 8;
        const float2 hsv = *(const float2*)&hb[(size_t)(i0 + n2) * IN_F + 2 * lane];
        *(float2*)&h_self[n2][2 * lane] = hsv;
    }
    __syncthreads();
    {
        const int o = t & (OUT_F - 1), fc = t >> 7;
        float acc[8];
        #pragma unroll
        for (int n = 0; n < 8; ++n) acc[n] = 0.0f;
        const int f0 = fc * (IN_F / 8);
        #pragma unroll
        for (int ff = 0; ff < IN_F / 8; ++ff) {
            const int f = f0 + ff;
            const float ws = Ws[f * OUT_F + o], wn = Wn[f * OUT_F + o];
            #pragma unroll
            for (int n = 0; n < 8; ++n) {
                acc[n] = fmaf(h_self[n][f], ws, acc[n]);
                acc[n] = fmaf(agg_s[n][f], wn, acc[n]);
            }
        }
        #pragma unroll
        for (int n = 0; n < 8; ++n) gemmp[fc][n][o] = acc[n];
    }
    __syncthreads();
    if (w < 8) {
        float x0 = bs[lane] + bn[lane];
        float x1 = bs[lane + 64] + bn[lane + 64];
        #pragma unroll
        for (int fcc = 0; fcc < 8; ++fcc) { x0 += gemmp[fcc][w][lane]; x1 += gemmp[fcc][w][lane + 64]; }
        float s = x0 + x1, s2 = x0 * x0 + x1 * x1;
        #pragma unroll
        for (int d = 32; d >= 1; d >>= 1) { s += __shfl_xor(s, d, 64); s2 += __shfl_xor(s2, d, 64); }
        const float mu = s * (1.0f / OUT_F);
        const float var = s2 * (1.0f / OUT_F) - mu * mu;
        const float rs = rsqrtf(var + 1e-5f);
        float* orow = out + (size_t)(base + w) * OUT_F;
        const float r0 = (x0 - mu) * rs * gamma[lane] + beta[lane];
        const float r1 = (x1 - mu) * rs * gamma[lane + 64] + beta[lane + 64];
        orow[lane] = fmaxf(r0, 0.0f);
        orow[lane + 64] = fmaxf(r1, 0.0f);
    }
}

extern "C" void kernel_launch(void* const* d_in, const int* in_sizes, int n_in,
                              void* d_out, int out_size, void* d_ws, size_t ws_size,
                              hipStream_t stream) {
    const float* h     = (const float*)d_in[0];
    const int*   adj   = (const int*)d_in[1];
    const float* Ws    = (const float*)d_in[2];
    const float* bs    = (const float*)d_in[3];
    const float* Wn    = (const float*)d_in[4];
    const float* bn    = (const float*)d_in[5];
    const float* gamma = (const float*)d_in[6];
    const float* beta  = (const float*)d_in[7];
    float* out = (float*)d_out;

    const long long bn_nodes = in_sizes[0] / IN_F;          // B*N
    const int N = (int)((long long)in_sizes[1] / bn_nodes); // adj is B*N*N
    const int B = (int)(bn_nodes / N);
    const int grid = (int)(bn_nodes / NPB);

    if (N == 1024) {
        float* wsval = (float*)d_ws;
        int*   wsidx = (int*)((char*)d_ws + (size_t)B * TOPD * 128 * 4);
        hipLaunchKernelGGL(topk_kernel, dim3(B * 128), dim3(64), 0, stream,
                           h, wsval, wsidx, N);
        hipLaunchKernelGGL(sage1024_kernel, dim3(grid), dim3(THREADS), 0, stream,
                           h, adj, Ws, bs, Wn, bn, gamma, beta, wsval, wsidx, out);
    } else {
        hipLaunchKernelGGL(sage_generic, dim3(grid), dim3(THREADS), 0, stream,
                           h, adj, Ws, bs, Wn, bn, gamma, beta, out, N);
    }
}

// Round 18
// 24.876 us; speedup vs baseline: 1.7497x; 1.0031x over previous
//
#include <hip/hip_runtime.h>
#include <cstdint>

#define IN_F 128
#define OUT_F 128
#define NPB 8        // nodes per block
#define WAVES 16
#define THREADS 1024
#define NEG_BIG -1e30f

typedef __fp16 h2v __attribute__((ext_vector_type(2)));
union H2U { unsigned u; h2v v; };
typedef _Float16 f16x8 __attribute__((ext_vector_type(8)));
typedef float f32x4 __attribute__((ext_vector_type(4)));
union F8U { unsigned u[4]; f16x8 v; };

// TN = compile-time N (1024), or 0 for runtime-generic fallback.
template<int TN>
__global__ __launch_bounds__(THREADS, 4) void sage_kernel(
    const float* __restrict__ h, const int* __restrict__ adj,
    const float* __restrict__ Ws, const float* __restrict__ bs,
    const float* __restrict__ Wn, const float* __restrict__ bn,
    const float* __restrict__ gamma, const float* __restrict__ beta,
    float* __restrict__ out, int Nrt)
{
    const int N = TN ? TN : Nrt;
    const int STRIP = N / WAVES;                 // 64 when N=1024

    __shared__ unsigned scanp[WAVES][NPB][64];   // 32 KB scan partials (f16x2)
    __shared__ __align__(16) char Xraw[16 * 512];// 8 KB: X[n][256] f16, swizzled
    __shared__ float outp[NPB][OUT_F];           // 4 KB pre-LN outputs
    __shared__ unsigned anyw_s[WAVES];

    const int t    = threadIdx.x;
    const int w    = t >> 6;
    const int lane = t & 63;

    const int base = blockIdx.x * NPB;
    const int b    = base / N;
    const int i0   = base - b * N;

    const float* hb   = h   + (size_t)b * N * IN_F;
    const int*   adjb = adj + (size_t)b * N * N;
    const int jbase   = w * STRIP;

    // ---- one u64 mask per node over this wave's 64-column strip ----
    unsigned long long m[NPB];
    unsigned anybits = 0;
    #pragma unroll
    for (int n = 0; n < NPB; ++n) {
        const int i_n = i0 + n;
        const int j   = jbase + lane;
        m[n] = __ballot(adjb[(size_t)i_n * N + j] != 0 && j != i_n);
        anybits |= (m[n] != 0ull ? 1u : 0u) << n;
    }

    const unsigned NEGINF2 = 0xFC00FC00u;        // (-inf,-inf) f16x2
    const unsigned POSINF2 = 0x7C007C00u;        // (+inf,+inf) f16x2

    H2U a[NPB];
    #pragma unroll
    for (int n = 0; n < NPB; ++n) a[n].u = NEGINF2;

    const float* hrow = hb + (size_t)jbase * IN_F + 2 * lane;

    if constexpr (TN == 1024) {
        // ---- fully unrolled: literal mask shifts, imm-offset load groups,
        //      fused cvt_pk -> packed f16 pk_min/pk_max ----
        #pragma unroll
        for (int g = 0; g < 8; ++g) {
            const float* p = hrow + g * 8 * IN_F;    // one base bump / 8 rows
            float2 vf[8];
            #pragma unroll
            for (int r = 0; r < 8; ++r)
                vf[r] = *(const float2*)(p + r * IN_F);  // imm offsets r*512B
            H2U vp[8];
            #pragma unroll
            for (int r = 0; r < 8; ++r)
                vp[r].v = __builtin_amdgcn_cvt_pkrtz(vf[r].x, vf[r].y);
            #pragma unroll
            for (int r = 0; r < 8; ++r) {
                #pragma unroll
                for (int n = 0; n < NPB; ++n) {
                    H2U cap;                       // s_bitcmp(literal)+s_cselect
                    cap.u = ((m[n] >> (g * 8 + r)) & 1ull) ? POSINF2 : NEGINF2;
                    a[n].v = __builtin_elementwise_max(a[n].v,
                                 __builtin_elementwise_min(vp[r].v, cap.v));
                }
            }
        }
    } else {
        for (int k = 0; k < STRIP; ++k) {
            const float2 vf = *(const float2*)(hrow + (size_t)k * IN_F);
            H2U vp; vp.v = __builtin_amdgcn_cvt_pkrtz(vf.x, vf.y);
            #pragma unroll
            for (int n = 0; n < NPB; ++n) {
                H2U cap; cap.u = ((m[n] >> k) & 1ull) ? POSINF2 : NEGINF2;
                a[n].v = __builtin_elementwise_max(a[n].v,
                             __builtin_elementwise_min(vp.v, cap.v));
            }
        }
    }

    #pragma unroll
    for (int n = 0; n < NPB; ++n) scanp[w][n][lane] = a[n].u;
    if (lane == 0) anyw_s[w] = anybits;
    __syncthreads();

    // ---- combine partials -> X agg half (waves 0-7); X self half (8-15) ----
    // X[n][k] f16, row = 512 B, byte offsets XOR-swizzled by ((n&7)<<4).
    if (w < NPB) {
        H2U r; r.u = scanp[0][w][lane];
        #pragma unroll
        for (int wp = 1; wp < WAVES; ++wp) {
            H2U p; p.u = scanp[wp][w][lane];
            r.v = __builtin_elementwise_max(r.v, p.v);
        }
        unsigned anyall = 0;
        #pragma unroll
        for (int wp = 0; wp < WAVES; ++wp) anyall |= anyw_s[wp];
        if (!((anyall >> w) & 1u)) {   // no neighbors -> self features
            const float2 hs = *(const float2*)&hb[(size_t)(i0 + w) * IN_F + 2 * lane];
            r.v = __builtin_amdgcn_cvt_pkrtz(hs.x, hs.y);
        }
        const unsigned byte = (unsigned)(w * 512 + 256 + lane * 4) ^ ((w & 7) << 4);
        *(unsigned*)(Xraw + byte) = r.u;
    } else {
        const int n2 = w - NPB;
        const float2 hs = *(const float2*)&hb[(size_t)(i0 + n2) * IN_F + 2 * lane];
        H2U p; p.v = __builtin_amdgcn_cvt_pkrtz(hs.x, hs.y);
        const unsigned byte = (unsigned)(n2 * 512 + lane * 4) ^ ((n2 & 7) << 4);
        *(unsigned*)(Xraw + byte) = p.u;
    }
    __syncthreads();

    // ---- MFMA epilogue: out(8x128) = X(8x256,f16) . [Ws;Wn](256x128,f16) ----
    // Wave w<8 owns o-tile [w*16, w*16+16). D = A.B: A[r][k]=W[k][w*16+r],
    // B[k][c]=X[c][k]. Lane: r/c = lane&15, k-group = lane>>4 (8 k's each).
    if (w < NPB) {
        const int col = lane & 15;
        const int kg  = lane >> 4;
        f32x4 acc = {0.f, 0.f, 0.f, 0.f};
        #pragma unroll
        for (int chunk = 0; chunk < 8; ++chunk) {
            const float* Wsrc = (chunk < 4) ? Ws : Wn;
            const int kbase = (chunk & 3) * 32 + kg * 8;
            float wv[8];
            #pragma unroll
            for (int j = 0; j < 8; ++j)
                wv[j] = Wsrc[(kbase + j) * OUT_F + w * 16 + col];
            F8U af;
            #pragma unroll
            for (int j2 = 0; j2 < 4; ++j2) {
                H2U pk; pk.v = __builtin_amdgcn_cvt_pkrtz(wv[2 * j2], wv[2 * j2 + 1]);
                af.u[j2] = pk.u;
            }
            const unsigned byte = (unsigned)(col * 512 + chunk * 64 + kg * 16) ^ ((col & 7) << 4);
            const uint4 braw = *(const uint4*)(Xraw + byte);
            F8U bf; bf.u[0] = braw.x; bf.u[1] = braw.y; bf.u[2] = braw.z; bf.u[3] = braw.w;
            acc = __builtin_amdgcn_mfma_f32_16x16x32_f16(af.v, bf.v, acc, 0, 0, 0);
        }
        if (col < NPB) {   // D[row=kg*4+q][col] = out[node col][o = w*16+kg*4+q]
            #pragma unroll
            for (int q = 0; q < 4; ++q)
                outp[col][w * 16 + kg * 4 + q] = acc[q];
        }
    }
    __syncthreads();

    // ---- bias + LayerNorm + ReLU (waves 0-7, node w) ----
    if (w < NPB) {
        float x0 = bs[lane]      + bn[lane]      + outp[w][lane];
        float x1 = bs[lane + 64] + bn[lane + 64] + outp[w][lane + 64];
        float s  = x0 + x1;
        float s2 = x0 * x0 + x1 * x1;
        #pragma unroll
        for (int d = 32; d >= 1; d >>= 1) {
            s  += __shfl_xor(s, d, 64);
            s2 += __shfl_xor(s2, d, 64);
        }
        const float mu  = s * (1.0f / OUT_F);
        const float var = s2 * (1.0f / OUT_F) - mu * mu;
        const float rs  = rsqrtf(var + 1e-5f);

        float* orow = out + (size_t)(base + w) * OUT_F;
        const float r0 = (x0 - mu) * rs * gamma[lane]      + beta[lane];
        const float r1 = (x1 - mu) * rs * gamma[lane + 64] + beta[lane + 64];
        orow[lane]      = fmaxf(r0, 0.0f);
        orow[lane + 64] = fmaxf(r1, 0.0f);
    }
}

extern "C" void kernel_launch(void* const* d_in, const int* in_sizes, int n_in,
                              void* d_out, int out_size, void* d_ws, size_t ws_size,
                              hipStream_t stream) {
    const float* h     = (const float*)d_in[0];
    const int*   adj   = (const int*)d_in[1];
    const float* Ws    = (const float*)d_in[2];
    const float* bs    = (const float*)d_in[3];
    const float* Wn    = (const float*)d_in[4];
    const float* bn    = (const float*)d_in[5];
    const float* gamma = (const float*)d_in[6];
    const float* beta  = (const float*)d_in[7];
    float* out = (float*)d_out;

    const long long bn_nodes = in_sizes[0] / IN_F;          // B*N
    const int N = (int)((long long)in_sizes[1] / bn_nodes); // adj is B*N*N
    const int grid = (int)(bn_nodes / NPB);

    if (N == 1024) {
        hipLaunchKernelGGL(sage_kernel<1024>, dim3(grid), dim3(THREADS), 0, stream,
                           h, adj, Ws, bs, Wn, bn, gamma, beta, out, N);
    } else {
        hipLaunchKernelGGL(sage_kernel<0>, dim3(grid), dim3(THREADS), 0, stream,
                           h, adj, Ws, bs, Wn, bn, gamma, beta, out, N);
    }
}